// Round 1
// baseline (528.107 us; speedup 1.0000x reference)
//
#include <hip/hip_runtime.h>
#include <hip/hip_bf16.h>
#include <math.h>

#define L 2048
#define DM 1024
#define ED 2048
#define NST 16
#define DTR 64
#define BETA 0.6f
#define NCHUNK 32
#define LCH 64            // L / NCHUNK

typedef __bf16 bf16_t;
typedef __bf16 bf16x8 __attribute__((ext_vector_type(8)));
typedef __bf16 bf16x4 __attribute__((ext_vector_type(4)));
typedef float  floatx4 __attribute__((ext_vector_type(4)));

// ---------------- utility kernels ----------------

__global__ void k_fill(float* __restrict__ p, float v, int n) {
    int i = blockIdx.x * 256 + threadIdx.x;
    if (i < n) p[i] = v;
}

// fp32 -> bf16, 4 elements per thread
__global__ void k_cvt4(const float4* __restrict__ src, bf16x4* __restrict__ dst, int n4) {
    int i = blockIdx.x * 256 + threadIdx.x;
    if (i < n4) {
        float4 f = src[i];
        bf16x4 o;
        o[0] = (bf16_t)f.x; o[1] = (bf16_t)f.y; o[2] = (bf16_t)f.z; o[3] = (bf16_t)f.w;
        dst[i] = o;
    }
}

// ---------------- bf16 GEMM-BT:  C(M,N) = X(M,K) @ W(N,K)^T ----------------
// EPI 0: plain fp32 store.  EPI 1: softplus(v + bias[col]).
// Requires M%128==0, K%32==0. N may be ragged (guarded loads/stores).
template<int EPI>
__global__ __launch_bounds__(256)
void k_gemm_bt(const bf16_t* __restrict__ X, const bf16_t* __restrict__ W,
               float* __restrict__ C, int M, int N, int K,
               const float* __restrict__ bias) {
    __shared__ bf16_t As[128 * 32];
    __shared__ bf16_t Bs[128 * 32];
    const int tid  = threadIdx.x;
    const int bx   = blockIdx.x, by = blockIdx.y;
    const int wave = tid >> 6, lane = tid & 63;
    const int wm   = (wave >> 1) * 64;      // wave m-offset in tile
    const int wn   = (wave & 1) * 64;       // wave n-offset in tile
    const int quad = lane >> 4, l16 = lane & 15;

    floatx4 acc[4][4];
#pragma unroll
    for (int i = 0; i < 4; i++)
#pragma unroll
        for (int j = 0; j < 4; j++)
            acc[i][j] = (floatx4){0.f, 0.f, 0.f, 0.f};

    for (int kt = 0; kt < K; kt += 32) {
#pragma unroll
        for (int p = 0; p < 2; p++) {
            int e = p * 2048 + tid * 8;
            int r = e >> 5, c = e & 31;
            int arow = by * 128 + r;
            *(float4*)(&As[r * 32 + c]) =
                *(const float4*)(&X[(size_t)arow * K + kt + c]);
            int brow = bx * 128 + r;
            float4 bv = make_float4(0.f, 0.f, 0.f, 0.f);
            if (brow < N) bv = *(const float4*)(&W[(size_t)brow * K + kt + c]);
            *(float4*)(&Bs[r * 32 + c]) = bv;
        }
        __syncthreads();

        bf16x8 af[4], bfr[4];
#pragma unroll
        for (int mt = 0; mt < 4; mt++)
            af[mt] = *(const bf16x8*)(&As[(wm + mt * 16 + l16) * 32 + quad * 8]);
#pragma unroll
        for (int nt = 0; nt < 4; nt++)
            bfr[nt] = *(const bf16x8*)(&Bs[(wn + nt * 16 + l16) * 32 + quad * 8]);
#pragma unroll
        for (int mt = 0; mt < 4; mt++)
#pragma unroll
            for (int nt = 0; nt < 4; nt++)
                acc[mt][nt] = __builtin_amdgcn_mfma_f32_16x16x32_bf16(
                    af[mt], bfr[nt], acc[mt][nt], 0, 0, 0);
        __syncthreads();
    }

    // epilogue: D layout col = lane&15, row = quad*4 + reg
#pragma unroll
    for (int mt = 0; mt < 4; mt++) {
#pragma unroll
        for (int nt = 0; nt < 4; nt++) {
            int col = bx * 128 + wn + nt * 16 + l16;
            if (col < N) {
#pragma unroll
                for (int r4 = 0; r4 < 4; r4++) {
                    int row = by * 128 + wm + mt * 16 + quad * 4 + r4;
                    float v = acc[mt][nt][r4];
                    if (EPI == 1) {
                        v += bias[col];
                        v = (v > 20.f) ? v : log1pf(__expf(v));
                    }
                    C[(size_t)row * N + col] = v;
                }
            }
        }
    }
}

// ---------------- depthwise causal conv (K=4) + silu ----------------
// reads xz[:, 0:ED], writes xc fp32 and xc_bf
__global__ void k_conv_silu(const float* __restrict__ xz,
                            const float* __restrict__ conv_w,
                            const float* __restrict__ conv_b,
                            float* __restrict__ xc, bf16_t* __restrict__ xc_bf) {
    int idx = blockIdx.x * 256 + threadIdx.x;   // over L*ED
    int e = idx & (ED - 1);
    int t = idx >> 11;
    float w0 = conv_w[e * 4 + 0], w1 = conv_w[e * 4 + 1];
    float w2 = conv_w[e * 4 + 2], w3 = conv_w[e * 4 + 3];
    const float* col = xz + e;
    float acc = conv_b[e];
    if (t >= 3) acc += w0 * col[(size_t)(t - 3) * 4096];
    if (t >= 2) acc += w1 * col[(size_t)(t - 2) * 4096];
    if (t >= 1) acc += w2 * col[(size_t)(t - 1) * 4096];
    acc += w3 * col[(size_t)t * 4096];
    float s = acc / (1.f + __expf(-acc));       // silu
    xc[idx] = s;
    xc_bf[idx] = (bf16_t)s;
}

// dBC[:, 0:64] -> bf16 (input of delta GEMM)
__global__ void k_dly(const float* __restrict__ dBC, bf16_t* __restrict__ dly) {
    int idx = blockIdx.x * 256 + threadIdx.x;   // L*DTR
    int t = idx >> 6, r = idx & 63;
    dly[idx] = (bf16_t)dBC[t * 96 + r];
}

// ---------------- chunked scan ----------------
// recurrence per (e,n):  v_t = B*v_{t-1} + u_t ;  h_t = a_t*h_{t-1} + v_t
// M_t = [[a_t, B],[0, B]];  prefix P_i = [[p_i, q_i],[0, B^i]]
// p_i = a_i p_{i-1},  q_i = a_i q_{i-1} + B^i

__global__ void k_scan_p1(const float* __restrict__ delta, const float* __restrict__ xc,
                          const float* __restrict__ dBC, const float* __restrict__ A_log,
                          float4* __restrict__ summ) {
    int tid = blockIdx.x * 256 + threadIdx.x;   // NCHUNK*ED threads
    int e = tid & (ED - 1);
    int chunk = tid >> 11;
    float A[NST];
#pragma unroll
    for (int n = 0; n < NST; n++) A[n] = -__expf(A_log[e * NST + n]);
    float h[NST], v[NST], p[NST], q[NST];
#pragma unroll
    for (int n = 0; n < NST; n++) { h[n] = 0.f; v[n] = 0.f; q[n] = 0.f; p[n] = 1.f; }
    float bp = 1.f;
    int t0 = chunk * LCH;
    for (int i = 0; i < LCH; i++) {
        int t = t0 + i;
        float d   = delta[(size_t)t * ED + e];
        float xcv = xc[(size_t)t * ED + e];
        float du  = d * xcv;
        bp *= BETA;
        const float4* B4 = (const float4*)(&dBC[t * 96 + 64]);
        float Bv[NST];
#pragma unroll
        for (int j = 0; j < 4; j++) {
            float4 b = B4[j];
            Bv[4*j] = b.x; Bv[4*j+1] = b.y; Bv[4*j+2] = b.z; Bv[4*j+3] = b.w;
        }
#pragma unroll
        for (int n = 0; n < NST; n++) {
            float a = __expf(d * A[n]);
            float u = du * Bv[n];
            v[n] = BETA * v[n] + u;
            h[n] = a * h[n] + v[n];
            p[n] *= a;
            q[n] = a * q[n] + bp;
        }
    }
    size_t base = ((size_t)chunk * ED + e) * NST;
#pragma unroll
    for (int n = 0; n < NST; n++) summ[base + n] = make_float4(h[n], v[n], p[n], q[n]);
}

__global__ void k_combine(const float4* __restrict__ summ, float2* __restrict__ s0) {
    int tid = blockIdx.x * 256 + threadIdx.x;   // ED*NST threads, tid = e*16+n
    float h = 0.f, v = 0.f;
    const float bl = 6.3338280e-15f;            // 0.6^64
    for (int c = 0; c < NCHUNK; c++) {
        size_t idx = (size_t)c * ED * NST + tid;
        s0[idx] = make_float2(h, v);            // state entering chunk c
        float4 f = summ[idx];                   // (hL, vL, p, q)
        float hn = f.z * h + f.w * v + f.x;
        v = bl * v + f.y;
        h = hn;
    }
}

__global__ void k_scan_p2(const float* __restrict__ delta, const float* __restrict__ xc,
                          const float* __restrict__ dBC, const float* __restrict__ A_log,
                          const float2* __restrict__ s0, const float* __restrict__ Dvec,
                          float* __restrict__ y) {
    int tid = blockIdx.x * 256 + threadIdx.x;
    int e = tid & (ED - 1);
    int chunk = tid >> 11;
    float A[NST];
#pragma unroll
    for (int n = 0; n < NST; n++) A[n] = -__expf(A_log[e * NST + n]);
    float h0[NST], v0[NST];
    size_t sbase = ((size_t)chunk * ED + e) * NST;
#pragma unroll
    for (int n = 0; n < NST; n++) { float2 s = s0[sbase + n]; h0[n] = s.x; v0[n] = s.y; }
    float De = Dvec[e];
    float h[NST], v[NST], p[NST], q[NST];
#pragma unroll
    for (int n = 0; n < NST; n++) { h[n] = 0.f; v[n] = 0.f; q[n] = 0.f; p[n] = 1.f; }
    float bp = 1.f;
    int t0 = chunk * LCH;
    for (int i = 0; i < LCH; i++) {
        int t = t0 + i;
        float d   = delta[(size_t)t * ED + e];
        float xcv = xc[(size_t)t * ED + e];
        float du  = d * xcv;
        bp *= BETA;
        const float4* B4 = (const float4*)(&dBC[t * 96 + 64]);
        const float4* C4 = (const float4*)(&dBC[t * 96 + 80]);
        float Bv[NST], Cv[NST];
#pragma unroll
        for (int j = 0; j < 4; j++) {
            float4 b = B4[j];
            Bv[4*j] = b.x; Bv[4*j+1] = b.y; Bv[4*j+2] = b.z; Bv[4*j+3] = b.w;
            float4 c = C4[j];
            Cv[4*j] = c.x; Cv[4*j+1] = c.y; Cv[4*j+2] = c.z; Cv[4*j+3] = c.w;
        }
        float yacc = 0.f;
#pragma unroll
        for (int n = 0; n < NST; n++) {
            float a = __expf(d * A[n]);
            float u = du * Bv[n];
            v[n] = BETA * v[n] + u;
            h[n] = a * h[n] + v[n];
            p[n] *= a;
            q[n] = a * q[n] + bp;
            float ht = h[n] + p[n] * h0[n] + q[n] * v0[n];
            yacc += Cv[n] * ht;
        }
        y[(size_t)t * ED + e] = yacc + De * xcv;
    }
}

// g = bf16(y * silu(z)),  z = xz[:, ED:2ED]
__global__ void k_gate(const float* __restrict__ y, const float* __restrict__ xz,
                       bf16_t* __restrict__ g) {
    int idx = blockIdx.x * 256 + threadIdx.x;   // L*ED
    int t = idx >> 11, e = idx & (ED - 1);
    float z = xz[(size_t)t * 4096 + ED + e];
    float s = z / (1.f + __expf(-z));
    g[idx] = (bf16_t)(y[idx] * s);
}

// ---------------- launch ----------------

extern "C" void kernel_launch(void* const* d_in, const int* in_sizes, int n_in,
                              void* d_out, int out_size, void* d_ws, size_t ws_size,
                              hipStream_t stream) {
    const float* x      = (const float*)d_in[0];
    const float* W_in   = (const float*)d_in[1];
    const float* conv_w = (const float*)d_in[2];
    const float* conv_b = (const float*)d_in[3];
    const float* W_x    = (const float*)d_in[4];
    const float* W_dt   = (const float*)d_in[5];
    const float* b_dt   = (const float*)d_in[6];
    const float* A_log  = (const float*)d_in[7];
    const float* Dv     = (const float*)d_in[8];
    const float* W_out  = (const float*)d_in[9];
    float* out = (float*)d_out;

    // workspace layout (bytes, all 256-aligned); lifetime-based aliasing
    constexpr size_t OFF_XZ    = 0;           // 33554432  xz (L,4096) f32
    constexpr size_t OFF_XC    = 33554432;    // 16777216  xc f32
    constexpr size_t OFF_XCBF  = 50331648;    //  8388608  xc bf16
    constexpr size_t OFF_DELTA = 58720256;    // 16777216  delta f32
    constexpr size_t OFF_SUMMY = 75497472;    // 16777216  summ (p1/comb) then y (p2+)
    constexpr size_t OFF_S0    = 92274688;    //  8388608  chunk-initial states
    constexpr size_t OFF_DBC   = 100663296;   //   786432  dBC (L,96) f32
    constexpr size_t OFF_DLY   = 101449728;   //   262144  delta_r bf16
    constexpr size_t OFF_XBF_G = 101711872;   //  8388608  x_bf then g_bf
    constexpr size_t OFF_WINOUT= 110100480;   //  8388608  Win_bf then Wout_bf
    constexpr size_t OFF_WXBF  = 118489088;   //   393216
    constexpr size_t OFF_WDTBF = 118882304;   //   262144
    constexpr size_t WS_NEED   = 119144448;

    if (ws_size < WS_NEED) {   // loud, diagnosable failure
        k_fill<<<(out_size + 255) / 256, 256, 0, stream>>>(out, 1.0e9f, out_size);
        return;
    }

    char* ws = (char*)d_ws;
    float*  xz    = (float*)(ws + OFF_XZ);
    float*  xc    = (float*)(ws + OFF_XC);
    bf16_t* xc_bf = (bf16_t*)(ws + OFF_XCBF);
    float*  delta = (float*)(ws + OFF_DELTA);
    float4* summ  = (float4*)(ws + OFF_SUMMY);
    float*  y     = (float*)(ws + OFF_SUMMY);   // alias: summ dead after combine
    float2* s0    = (float2*)(ws + OFF_S0);
    float*  dBC   = (float*)(ws + OFF_DBC);
    bf16_t* dly   = (bf16_t*)(ws + OFF_DLY);
    bf16_t* x_bf  = (bf16_t*)(ws + OFF_XBF_G);
    bf16_t* g_bf  = (bf16_t*)(ws + OFF_XBF_G);  // alias: x_bf dead after GEMM1
    bf16_t* Win_bf  = (bf16_t*)(ws + OFF_WINOUT);
    bf16_t* Wout_bf = (bf16_t*)(ws + OFF_WINOUT); // alias: Win_bf dead after GEMM1
    bf16_t* Wx_bf   = (bf16_t*)(ws + OFF_WXBF);
    bf16_t* Wdt_bf  = (bf16_t*)(ws + OFF_WDTBF);

    auto cvt = [&](const float* s, bf16_t* d, int n) {
        k_cvt4<<<(n / 4 + 255) / 256, 256, 0, stream>>>((const float4*)s, (bf16x4*)d, n / 4);
    };

    // convert inputs needed before GEMM1
    cvt(x, x_bf, L * DM);
    cvt(W_in, Win_bf, 2 * ED * DM);
    cvt(W_x, Wx_bf, 96 * ED);
    cvt(W_dt, Wdt_bf, ED * DTR);

    // GEMM1: xz = x @ W_in^T   (M=L, N=4096, K=DM)
    {
        dim3 g(4096 / 128, L / 128);
        k_gemm_bt<0><<<g, 256, 0, stream>>>(x_bf, Win_bf, xz, L, 4096, DM, nullptr);
    }
    // conv + silu -> xc (f32 + bf16)
    k_conv_silu<<<L * ED / 256, 256, 0, stream>>>(xz, conv_w, conv_b, xc, xc_bf);
    // GEMM2: dBC = xc @ W_x^T  (M=L, N=96, K=ED)
    {
        dim3 g(1, L / 128);
        k_gemm_bt<0><<<g, 256, 0, stream>>>(xc_bf, Wx_bf, dBC, L, 96, ED, nullptr);
    }
    k_dly<<<L * DTR / 256, 256, 0, stream>>>(dBC, dly);
    // GEMM3: delta = softplus(dly @ W_dt^T + b_dt)  (M=L, N=ED, K=64)
    {
        dim3 g(ED / 128, L / 128);
        k_gemm_bt<1><<<g, 256, 0, stream>>>(dly, Wdt_bf, delta, L, ED, DTR, b_dt);
    }
    // chunked scan
    k_scan_p1<<<NCHUNK * ED / 256, 256, 0, stream>>>(delta, xc, dBC, A_log, summ);
    k_combine<<<ED * NST / 256, 256, 0, stream>>>(summ, s0);
    k_scan_p2<<<NCHUNK * ED / 256, 256, 0, stream>>>(delta, xc, dBC, A_log, s0, Dv, y);
    // gate + convert W_out (Win_bf region is free now)
    cvt(W_out, Wout_bf, DM * ED);
    k_gate<<<L * ED / 256, 256, 0, stream>>>(y, xz, g_bf);
    // GEMM4: out = g @ W_out^T  (M=L, N=DM, K=ED)
    {
        dim3 g(DM / 128, L / 128);
        k_gemm_bt<0><<<g, 256, 0, stream>>>(g_bf, Wout_bf, out, L, DM, ED, nullptr);
    }
}

// Round 2
// 429.391 us; speedup vs baseline: 1.2299x; 1.2299x over previous
//
#include <hip/hip_runtime.h>
#include <hip/hip_bf16.h>
#include <math.h>

#define L 2048
#define DM 1024
#define ED 2048
#define NST 16
#define DTR 64
#define BETA 0.6f
#define NCHUNK 32
#define LCH 64            // L / NCHUNK

typedef __bf16 bf16_t;
typedef __bf16 bf16x8 __attribute__((ext_vector_type(8)));
typedef __bf16 bf16x4 __attribute__((ext_vector_type(4)));
typedef float  floatx4 __attribute__((ext_vector_type(4)));

// ---------------- utility kernels ----------------

__global__ void k_fill(float* __restrict__ p, float v, int n) {
    int i = blockIdx.x * 256 + threadIdx.x;
    if (i < n) p[i] = v;
}

// fp32 -> bf16, 4 elements per thread
__global__ void k_cvt4(const float4* __restrict__ src, bf16x4* __restrict__ dst, int n4) {
    int i = blockIdx.x * 256 + threadIdx.x;
    if (i < n4) {
        float4 f = src[i];
        bf16x4 o;
        o[0] = (bf16_t)f.x; o[1] = (bf16_t)f.y; o[2] = (bf16_t)f.z; o[3] = (bf16_t)f.w;
        dst[i] = o;
    }
}

// ---------------- bf16 GEMM-BT:  C(M,N) = X(M,K) @ W(N,K)^T ----------------
template<int EPI>
__global__ __launch_bounds__(256)
void k_gemm_bt(const bf16_t* __restrict__ X, const bf16_t* __restrict__ W,
               float* __restrict__ C, int M, int N, int K,
               const float* __restrict__ bias) {
    __shared__ bf16_t As[128 * 32];
    __shared__ bf16_t Bs[128 * 32];
    const int tid  = threadIdx.x;
    const int bx   = blockIdx.x, by = blockIdx.y;
    const int wave = tid >> 6, lane = tid & 63;
    const int wm   = (wave >> 1) * 64;      // wave m-offset in tile
    const int wn   = (wave & 1) * 64;       // wave n-offset in tile
    const int quad = lane >> 4, l16 = lane & 15;

    floatx4 acc[4][4];
#pragma unroll
    for (int i = 0; i < 4; i++)
#pragma unroll
        for (int j = 0; j < 4; j++)
            acc[i][j] = (floatx4){0.f, 0.f, 0.f, 0.f};

    for (int kt = 0; kt < K; kt += 32) {
#pragma unroll
        for (int p = 0; p < 2; p++) {
            int e = p * 2048 + tid * 8;
            int r = e >> 5, c = e & 31;
            int arow = by * 128 + r;
            *(float4*)(&As[r * 32 + c]) =
                *(const float4*)(&X[(size_t)arow * K + kt + c]);
            int brow = bx * 128 + r;
            float4 bv = make_float4(0.f, 0.f, 0.f, 0.f);
            if (brow < N) bv = *(const float4*)(&W[(size_t)brow * K + kt + c]);
            *(float4*)(&Bs[r * 32 + c]) = bv;
        }
        __syncthreads();

        bf16x8 af[4], bfr[4];
#pragma unroll
        for (int mt = 0; mt < 4; mt++)
            af[mt] = *(const bf16x8*)(&As[(wm + mt * 16 + l16) * 32 + quad * 8]);
#pragma unroll
        for (int nt = 0; nt < 4; nt++)
            bfr[nt] = *(const bf16x8*)(&Bs[(wn + nt * 16 + l16) * 32 + quad * 8]);
#pragma unroll
        for (int mt = 0; mt < 4; mt++)
#pragma unroll
            for (int nt = 0; nt < 4; nt++)
                acc[mt][nt] = __builtin_amdgcn_mfma_f32_16x16x32_bf16(
                    af[mt], bfr[nt], acc[mt][nt], 0, 0, 0);
        __syncthreads();
    }

    // epilogue: D layout col = lane&15, row = quad*4 + reg
#pragma unroll
    for (int mt = 0; mt < 4; mt++) {
#pragma unroll
        for (int nt = 0; nt < 4; nt++) {
            int col = bx * 128 + wn + nt * 16 + l16;
            if (col < N) {
#pragma unroll
                for (int r4 = 0; r4 < 4; r4++) {
                    int row = by * 128 + wm + mt * 16 + quad * 4 + r4;
                    float v = acc[mt][nt][r4];
                    if (EPI == 1) {
                        v += bias[col];
                        v = (v > 20.f) ? v : log1pf(__expf(v));
                    }
                    C[(size_t)row * N + col] = v;
                }
            }
        }
    }
}

// ---------------- depthwise causal conv (K=4) + silu ----------------
__global__ void k_conv_silu(const float* __restrict__ xz,
                            const float* __restrict__ conv_w,
                            const float* __restrict__ conv_b,
                            float* __restrict__ xc, bf16_t* __restrict__ xc_bf) {
    int idx = blockIdx.x * 256 + threadIdx.x;   // over L*ED
    int e = idx & (ED - 1);
    int t = idx >> 11;
    float w0 = conv_w[e * 4 + 0], w1 = conv_w[e * 4 + 1];
    float w2 = conv_w[e * 4 + 2], w3 = conv_w[e * 4 + 3];
    const float* col = xz + e;
    float acc = conv_b[e];
    if (t >= 3) acc += w0 * col[(size_t)(t - 3) * 4096];
    if (t >= 2) acc += w1 * col[(size_t)(t - 2) * 4096];
    if (t >= 1) acc += w2 * col[(size_t)(t - 1) * 4096];
    acc += w3 * col[(size_t)t * 4096];
    float s = acc / (1.f + __expf(-acc));       // silu
    xc[idx] = s;
    xc_bf[idx] = (bf16_t)s;
}

// dBC[:, 0:64] -> bf16 (input of delta GEMM)
__global__ void k_dly(const float* __restrict__ dBC, bf16_t* __restrict__ dly) {
    int idx = blockIdx.x * 256 + threadIdx.x;   // L*DTR
    int t = idx >> 6, r = idx & 63;
    dly[idx] = (bf16_t)dBC[t * 96 + r];
}

// ---------------- chunked scan, n split across lanes ----------------
// thread = (chunk, e, n); lane bits: n = low 4 bits -> 16-way broadcast of
// delta/xc, contiguous B/C loads, coalesced summ/s0.
// recurrence per (e,n):  v_t = B*v_{t-1} + u_t ;  h_t = a_t*h_{t-1} + v_t

__global__ __launch_bounds__(256)
void k_scan_p1(const float* __restrict__ delta, const float* __restrict__ xc,
               const float* __restrict__ dBC, const float* __restrict__ A_log,
               float4* __restrict__ summ) {
    int tid = blockIdx.x * 256 + threadIdx.x;   // NCHUNK*ED*NST threads
    int n = tid & 15;
    int e = (tid >> 4) & (ED - 1);
    int chunk = tid >> 15;
    float A = -__expf(A_log[e * NST + n]);
    float h = 0.f, v = 0.f, p = 1.f, q = 0.f, bp = 1.f;
    int t0 = chunk * LCH;
    for (int i = 0; i < LCH; i++) {
        int t = t0 + i;
        float d   = delta[(size_t)t * ED + e];
        float xcv = xc[(size_t)t * ED + e];
        float Bv  = dBC[t * 96 + 64 + n];
        bp *= BETA;
        float a = __expf(d * A);
        float u = d * xcv * Bv;
        v = BETA * v + u;
        h = a * h + v;
        p *= a;
        q = a * q + bp;
    }
    summ[((size_t)chunk * ED + e) * NST + n] = make_float4(h, v, p, q);
}

__global__ void k_combine(const float4* __restrict__ summ, float2* __restrict__ s0) {
    int tid = blockIdx.x * 256 + threadIdx.x;   // ED*NST threads, tid = e*16+n
    float h = 0.f, v = 0.f;
    const float bl = 6.3338280e-15f;            // 0.6^64
    for (int c = 0; c < NCHUNK; c++) {
        size_t idx = (size_t)c * ED * NST + tid;
        s0[idx] = make_float2(h, v);            // state entering chunk c
        float4 f = summ[idx];                   // (hL, vL, p, q)
        float hn = f.z * h + f.w * v + f.x;
        v = bl * v + f.y;
        h = hn;
    }
}

__global__ __launch_bounds__(256)
void k_scan_p2(const float* __restrict__ delta, const float* __restrict__ xc,
               const float* __restrict__ dBC, const float* __restrict__ A_log,
               const float2* __restrict__ s0, const float* __restrict__ Dvec,
               float* __restrict__ y) {
    int tid = blockIdx.x * 256 + threadIdx.x;
    int n = tid & 15;
    int e = (tid >> 4) & (ED - 1);
    int chunk = tid >> 15;
    float A = -__expf(A_log[e * NST + n]);
    float2 s = s0[((size_t)chunk * ED + e) * NST + n];
    float h0 = s.x, v0 = s.y;
    float De = Dvec[e];
    float h = 0.f, v = 0.f, p = 1.f, q = 0.f, bp = 1.f;
    int t0 = chunk * LCH;
    for (int i = 0; i < LCH; i++) {
        int t = t0 + i;
        float d   = delta[(size_t)t * ED + e];
        float xcv = xc[(size_t)t * ED + e];
        float Bv  = dBC[t * 96 + 64 + n];
        float Cv  = dBC[t * 96 + 80 + n];
        bp *= BETA;
        float a = __expf(d * A);
        float u = d * xcv * Bv;
        v = BETA * v + u;
        h = a * h + v;
        p *= a;
        q = a * q + bp;
        float ht = h + p * h0 + q * v0;
        float part = Cv * ht;
        // reduce over the 16 n-lanes (lanes n..n+15 of this 16-group)
        part += __shfl_xor(part, 1, 16);
        part += __shfl_xor(part, 2, 16);
        part += __shfl_xor(part, 4, 16);
        part += __shfl_xor(part, 8, 16);
        if (n == 0) y[(size_t)t * ED + e] = part + De * xcv;
    }
}

// g = bf16(y * silu(z)),  z = xz[:, ED:2ED]
__global__ void k_gate(const float* __restrict__ y, const float* __restrict__ xz,
                       bf16_t* __restrict__ g) {
    int idx = blockIdx.x * 256 + threadIdx.x;   // L*ED
    int t = idx >> 11, e = idx & (ED - 1);
    float z = xz[(size_t)t * 4096 + ED + e];
    float s = z / (1.f + __expf(-z));
    g[idx] = (bf16_t)(y[idx] * s);
}

// ---------------- launch ----------------

extern "C" void kernel_launch(void* const* d_in, const int* in_sizes, int n_in,
                              void* d_out, int out_size, void* d_ws, size_t ws_size,
                              hipStream_t stream) {
    const float* x      = (const float*)d_in[0];
    const float* W_in   = (const float*)d_in[1];
    const float* conv_w = (const float*)d_in[2];
    const float* conv_b = (const float*)d_in[3];
    const float* W_x    = (const float*)d_in[4];
    const float* W_dt   = (const float*)d_in[5];
    const float* b_dt   = (const float*)d_in[6];
    const float* A_log  = (const float*)d_in[7];
    const float* Dv     = (const float*)d_in[8];
    const float* W_out  = (const float*)d_in[9];
    float* out = (float*)d_out;

    // workspace layout (bytes, all 256-aligned); lifetime-based aliasing
    constexpr size_t OFF_XZ    = 0;           // 33554432  xz (L,4096) f32
    constexpr size_t OFF_XC    = 33554432;    // 16777216  xc f32
    constexpr size_t OFF_XCBF  = 50331648;    //  8388608  xc bf16
    constexpr size_t OFF_DELTA = 58720256;    // 16777216  delta f32
    constexpr size_t OFF_SUMMY = 75497472;    // 16777216  summ (p1/comb) then y (p2+)
    constexpr size_t OFF_S0    = 92274688;    //  8388608  chunk-initial states
    constexpr size_t OFF_DBC   = 100663296;   //   786432  dBC (L,96) f32
    constexpr size_t OFF_DLY   = 101449728;   //   262144  delta_r bf16
    constexpr size_t OFF_XBF_G = 101711872;   //  8388608  x_bf then g_bf
    constexpr size_t OFF_WINOUT= 110100480;   //  8388608  Win_bf then Wout_bf
    constexpr size_t OFF_WXBF  = 118489088;   //   393216
    constexpr size_t OFF_WDTBF = 118882304;   //   262144
    constexpr size_t WS_NEED   = 119144448;

    if (ws_size < WS_NEED) {   // loud, diagnosable failure
        k_fill<<<(out_size + 255) / 256, 256, 0, stream>>>(out, 1.0e9f, out_size);
        return;
    }

    char* ws = (char*)d_ws;
    float*  xz    = (float*)(ws + OFF_XZ);
    float*  xc    = (float*)(ws + OFF_XC);
    bf16_t* xc_bf = (bf16_t*)(ws + OFF_XCBF);
    float*  delta = (float*)(ws + OFF_DELTA);
    float4* summ  = (float4*)(ws + OFF_SUMMY);
    float*  y     = (float*)(ws + OFF_SUMMY);   // alias: summ dead after combine+p2 start
    float2* s0    = (float2*)(ws + OFF_S0);
    float*  dBC   = (float*)(ws + OFF_DBC);
    bf16_t* dly   = (bf16_t*)(ws + OFF_DLY);
    bf16_t* x_bf  = (bf16_t*)(ws + OFF_XBF_G);
    bf16_t* g_bf  = (bf16_t*)(ws + OFF_XBF_G);  // alias: x_bf dead after GEMM1
    bf16_t* Win_bf  = (bf16_t*)(ws + OFF_WINOUT);
    bf16_t* Wout_bf = (bf16_t*)(ws + OFF_WINOUT); // alias: Win_bf dead after GEMM1
    bf16_t* Wx_bf   = (bf16_t*)(ws + OFF_WXBF);
    bf16_t* Wdt_bf  = (bf16_t*)(ws + OFF_WDTBF);

    auto cvt = [&](const float* s, bf16_t* d, int n) {
        k_cvt4<<<(n / 4 + 255) / 256, 256, 0, stream>>>((const float4*)s, (bf16x4*)d, n / 4);
    };

    // convert inputs needed before GEMM1
    cvt(x, x_bf, L * DM);
    cvt(W_in, Win_bf, 2 * ED * DM);
    cvt(W_x, Wx_bf, 96 * ED);
    cvt(W_dt, Wdt_bf, ED * DTR);

    // GEMM1: xz = x @ W_in^T   (M=L, N=4096, K=DM)
    {
        dim3 g(4096 / 128, L / 128);
        k_gemm_bt<0><<<g, 256, 0, stream>>>(x_bf, Win_bf, xz, L, 4096, DM, nullptr);
    }
    // conv + silu -> xc (f32 + bf16)
    k_conv_silu<<<L * ED / 256, 256, 0, stream>>>(xz, conv_w, conv_b, xc, xc_bf);
    // GEMM2: dBC = xc @ W_x^T  (M=L, N=96, K=ED)
    {
        dim3 g(1, L / 128);
        k_gemm_bt<0><<<g, 256, 0, stream>>>(xc_bf, Wx_bf, dBC, L, 96, ED, nullptr);
    }
    k_dly<<<L * DTR / 256, 256, 0, stream>>>(dBC, dly);
    // GEMM3: delta = softplus(dly @ W_dt^T + b_dt)  (M=L, N=ED, K=64)
    {
        dim3 g(ED / 128, L / 128);
        k_gemm_bt<1><<<g, 256, 0, stream>>>(dly, Wdt_bf, delta, L, ED, DTR, b_dt);
    }
    // chunked scan — n split across lanes: NCHUNK*ED*NST threads
    k_scan_p1<<<NCHUNK * ED * NST / 256, 256, 0, stream>>>(delta, xc, dBC, A_log, summ);
    k_combine<<<ED * NST / 256, 256, 0, stream>>>(summ, s0);
    k_scan_p2<<<NCHUNK * ED * NST / 256, 256, 0, stream>>>(delta, xc, dBC, A_log, s0, Dv, y);
    // gate + convert W_out (Win_bf region is free now)
    cvt(W_out, Wout_bf, DM * ED);
    k_gate<<<L * ED / 256, 256, 0, stream>>>(y, xz, g_bf);
    // GEMM4: out = g @ W_out^T  (M=L, N=DM, K=ED)
    {
        dim3 g(DM / 128, L / 128);
        k_gemm_bt<0><<<g, 256, 0, stream>>>(g_bf, Wout_bf, out, L, DM, ED, nullptr);
    }
}

// Round 3
// 295.954 us; speedup vs baseline: 1.7844x; 1.4509x over previous
//
#include <hip/hip_runtime.h>
#include <hip/hip_bf16.h>
#include <math.h>

#define L 2048
#define DM 1024
#define ED 2048
#define NST 16
#define DTR 64
#define BETA 0.6f
#define NCHUNK 64
#define LCH 32            // L / NCHUNK
#define SPLITS 16         // GEMM2 split-K

typedef __bf16 bf16_t;
typedef __bf16 bf16x8 __attribute__((ext_vector_type(8)));
typedef __bf16 bf16x4 __attribute__((ext_vector_type(4)));
typedef float  floatx4 __attribute__((ext_vector_type(4)));

// ---------------- utility kernels ----------------

__global__ void k_fill(float* __restrict__ p, float v, int n) {
    int i = blockIdx.x * 256 + threadIdx.x;
    if (i < n) p[i] = v;
}

__global__ void k_cvt4(const float4* __restrict__ src, bf16x4* __restrict__ dst, int n4) {
    int i = blockIdx.x * 256 + threadIdx.x;
    if (i < n4) {
        float4 f = src[i];
        bf16x4 o;
        o[0] = (bf16_t)f.x; o[1] = (bf16_t)f.y; o[2] = (bf16_t)f.z; o[3] = (bf16_t)f.w;
        dst[i] = o;
    }
}

// ---------------- bf16 GEMM-BT:  C(M,N) = X(M,K) @ W(N,K)^T ----------------
// GUARD=false: N%128==0, uses global_load_lds width-16 staging (m97 pattern).
// GUARD=true : ragged N (zero-fill B rows >= N, guarded stores), VGPR staging.
// blockIdx.z = split-K index: k range [z*ksz, z*ksz+ksz), C += z*M*ldc.
// EPI 0: plain store. EPI 1: softplus(v + bias[col]).
template<int EPI, bool GUARD>
__global__ __launch_bounds__(256)
void k_gemm_bt(const bf16_t* __restrict__ X, const bf16_t* __restrict__ W,
               float* __restrict__ C, int M, int N, int K, int ldc, int ksz,
               const float* __restrict__ bias) {
    __shared__ bf16_t As[128 * 32];
    __shared__ bf16_t Bs[128 * 32];
    const int tid  = threadIdx.x;
    const int bx   = blockIdx.x, by = blockIdx.y;
    const int kbase = blockIdx.z * ksz;
    C += (size_t)blockIdx.z * M * ldc;
    const int wave = tid >> 6, lane = tid & 63;
    const int wm   = (wave >> 1) * 64;
    const int wn   = (wave & 1) * 64;
    const int quad = lane >> 4, l16 = lane & 15;

    floatx4 acc[4][4];
#pragma unroll
    for (int i = 0; i < 4; i++)
#pragma unroll
        for (int j = 0; j < 4; j++)
            acc[i][j] = (floatx4){0.f, 0.f, 0.f, 0.f};

    for (int kt = kbase; kt < kbase + ksz; kt += 32) {
        if (GUARD) {
#pragma unroll
            for (int p = 0; p < 2; p++) {
                int e = p * 2048 + tid * 8;
                int r = e >> 5, c = e & 31;
                int arow = by * 128 + r;
                *(float4*)(&As[r * 32 + c]) =
                    *(const float4*)(&X[(size_t)arow * K + kt + c]);
                int brow = bx * 128 + r;
                float4 bv = make_float4(0.f, 0.f, 0.f, 0.f);
                if (brow < N) bv = *(const float4*)(&W[(size_t)brow * K + kt + c]);
                *(float4*)(&Bs[r * 32 + c]) = bv;
            }
        } else {
            // async global->LDS, 16B/lane; LDS dest = wave-uniform base + lane*16
#pragma unroll
            for (int p = 0; p < 2; p++) {
                int e = p * 2048 + tid * 8;     // bf16 elem idx; byte off = p*4096 + tid*16
                int r = e >> 5, c = e & 31;
                __builtin_amdgcn_global_load_lds(
                    (const __attribute__((address_space(1))) void*)&X[(size_t)(by * 128 + r) * K + kt + c],
                    (__attribute__((address_space(3))) void*)&As[e], 16, 0, 0);
                __builtin_amdgcn_global_load_lds(
                    (const __attribute__((address_space(1))) void*)&W[(size_t)(bx * 128 + r) * K + kt + c],
                    (__attribute__((address_space(3))) void*)&Bs[e], 16, 0, 0);
            }
        }
        __syncthreads();

        bf16x8 af[4], bfr[4];
#pragma unroll
        for (int mt = 0; mt < 4; mt++)
            af[mt] = *(const bf16x8*)(&As[(wm + mt * 16 + l16) * 32 + quad * 8]);
#pragma unroll
        for (int nt = 0; nt < 4; nt++)
            bfr[nt] = *(const bf16x8*)(&Bs[(wn + nt * 16 + l16) * 32 + quad * 8]);
#pragma unroll
        for (int mt = 0; mt < 4; mt++)
#pragma unroll
            for (int nt = 0; nt < 4; nt++)
                acc[mt][nt] = __builtin_amdgcn_mfma_f32_16x16x32_bf16(
                    af[mt], bfr[nt], acc[mt][nt], 0, 0, 0);
        __syncthreads();
    }

    // epilogue: D layout col = lane&15, row = quad*4 + reg
#pragma unroll
    for (int mt = 0; mt < 4; mt++) {
#pragma unroll
        for (int nt = 0; nt < 4; nt++) {
            int col = bx * 128 + wn + nt * 16 + l16;
            if (!GUARD || col < N) {
#pragma unroll
                for (int r4 = 0; r4 < 4; r4++) {
                    int row = by * 128 + wm + mt * 16 + quad * 4 + r4;
                    float v = acc[mt][nt][r4];
                    if (EPI == 1) {
                        v += bias[col];
                        v = (v > 20.f) ? v : log1pf(__expf(v));
                    }
                    C[(size_t)row * ldc + col] = v;
                }
            }
        }
    }
}

// ---------------- depthwise causal conv (K=4) + silu ----------------
__global__ void k_conv_silu(const float* __restrict__ xz,
                            const float* __restrict__ conv_w,
                            const float* __restrict__ conv_b,
                            float* __restrict__ xc, bf16_t* __restrict__ xc_bf) {
    int idx = blockIdx.x * 256 + threadIdx.x;   // over L*ED
    int e = idx & (ED - 1);
    int t = idx >> 11;
    float w0 = conv_w[e * 4 + 0], w1 = conv_w[e * 4 + 1];
    float w2 = conv_w[e * 4 + 2], w3 = conv_w[e * 4 + 3];
    const float* col = xz + e;
    float acc = conv_b[e];
    if (t >= 3) acc += w0 * col[(size_t)(t - 3) * 4096];
    if (t >= 2) acc += w1 * col[(size_t)(t - 2) * 4096];
    if (t >= 1) acc += w2 * col[(size_t)(t - 1) * 4096];
    acc += w3 * col[(size_t)t * 4096];
    float s = acc / (1.f + __expf(-acc));       // silu
    xc[idx] = s;
    xc_bf[idx] = (bf16_t)s;
}

// reduce GEMM2 split-K partials -> dBC fp32; also emit dly bf16 (cols 0:64)
__global__ void k_red2(const float* __restrict__ part, float* __restrict__ dBC,
                       bf16_t* __restrict__ dly) {
    int idx = blockIdx.x * 256 + threadIdx.x;   // L*96
    int t = idx / 96, c = idx - t * 96;
    float s = 0.f;
#pragma unroll
    for (int sp = 0; sp < SPLITS; sp++) s += part[(size_t)sp * L * 96 + idx];
    dBC[idx] = s;
    if (c < 64) dly[t * 64 + c] = (bf16_t)s;
}

// ---------------- chunked scan: thread = (chunk, e), 16 n-states in regs ----
// recurrence per (e,n):  v_t = B*v_{t-1} + u_t ;  h_t = a_t*h_{t-1} + v_t
// pass1 computes transition summary (h,v,p,q) per chunk with zero init;
// combine turns summaries into incoming states (written in-place into .xy);
// pass2 re-runs the recurrence from the true incoming state and emits gated g.
// summ layout: [n][chunk][e] float4 -> coalesced per-instr access everywhere.

__global__ __launch_bounds__(256)
void k_scan_p1(const float* __restrict__ delta, const float* __restrict__ xc,
               const float* __restrict__ dBC, const float* __restrict__ A_log,
               float4* __restrict__ summ) {
    const int chunk = blockIdx.x >> 3;                 // 8 blocks per chunk
    const int e = (blockIdx.x & 7) * 256 + threadIdx.x;
    float A[NST];
#pragma unroll
    for (int n = 0; n < NST; n++) A[n] = -__expf(A_log[e * NST + n]);
    float h[NST], v[NST], p[NST], q[NST];
#pragma unroll
    for (int n = 0; n < NST; n++) { h[n] = 0.f; v[n] = 0.f; p[n] = 1.f; q[n] = 0.f; }
    float bp = 1.f;
    const int t0 = chunk * LCH;
    for (int i = 0; i < LCH; i++) {
        int t = t0 + i;                                // block-uniform
        float d   = delta[(size_t)t * ED + e];
        float xcv = xc[(size_t)t * ED + e];
        float du  = d * xcv;
        bp *= BETA;
        const float* Bp = &dBC[t * 96 + 64];           // wave-uniform -> scalar loads
#pragma unroll
        for (int n = 0; n < NST; n++) {
            float a = __expf(d * A[n]);
            v[n] = BETA * v[n] + du * Bp[n];
            h[n] = a * h[n] + v[n];
            p[n] *= a;
            q[n] = a * q[n] + bp;
        }
    }
#pragma unroll
    for (int n = 0; n < NST; n++)
        summ[((size_t)n * NCHUNK + chunk) * ED + e] = make_float4(h[n], v[n], p[n], q[n]);
}

// sequential over chunks; writes incoming state (h,v) in-place into summ .xy
__global__ void k_combine(float4* __restrict__ summ) {
    int tid = blockIdx.x * 256 + threadIdx.x;   // ED*NST threads; tid = n*ED + e
    int n = tid >> 11, e = tid & (ED - 1);
    float2* s2 = (float2*)summ;
    float h = 0.f, v = 0.f;
    const float bl = 7.9586611e-8f;             // 0.6^32
#pragma unroll 4
    for (int c = 0; c < NCHUNK; c++) {
        size_t idx = ((size_t)n * NCHUNK + c) * ED + e;
        float4 f = summ[idx];                   // (hL, vL, p, q)
        s2[idx * 2] = make_float2(h, v);        // incoming state for chunk c
        float hn = f.z * h + f.w * v + f.x;
        v = bl * v + f.y;
        h = hn;
    }
}

__global__ __launch_bounds__(256)
void k_scan_p2(const float* __restrict__ delta, const float* __restrict__ xc,
               const float* __restrict__ dBC, const float* __restrict__ A_log,
               const float4* __restrict__ summ, const float* __restrict__ Dvec,
               const float* __restrict__ xz, bf16_t* __restrict__ g) {
    const int chunk = blockIdx.x >> 3;
    const int e = (blockIdx.x & 7) * 256 + threadIdx.x;
    float A[NST];
#pragma unroll
    for (int n = 0; n < NST; n++) A[n] = -__expf(A_log[e * NST + n]);
    float h[NST], v[NST];
    const float2* s2 = (const float2*)summ;
#pragma unroll
    for (int n = 0; n < NST; n++) {
        float2 s = s2[(((size_t)n * NCHUNK + chunk) * ED + e) * 2];
        h[n] = s.x; v[n] = s.y;                 // true incoming state: no p/q needed
    }
    const float De = Dvec[e];
    const int t0 = chunk * LCH;
    for (int i = 0; i < LCH; i++) {
        int t = t0 + i;
        float d   = delta[(size_t)t * ED + e];
        float xcv = xc[(size_t)t * ED + e];
        float du  = d * xcv;
        const float* Bp = &dBC[t * 96 + 64];
        const float* Cp = &dBC[t * 96 + 80];
        float yacc = 0.f;
#pragma unroll
        for (int n = 0; n < NST; n++) {
            float a = __expf(d * A[n]);
            v[n] = BETA * v[n] + du * Bp[n];
            h[n] = a * h[n] + v[n];
            yacc += Cp[n] * h[n];
        }
        // fused gate: g = bf16((y + D*xc) * silu(z))
        float z = xz[(size_t)t * 4096 + ED + e];
        float sz = z / (1.f + __expf(-z));
        g[(size_t)t * ED + e] = (bf16_t)((yacc + De * xcv) * sz);
    }
}

// ---------------- launch ----------------

extern "C" void kernel_launch(void* const* d_in, const int* in_sizes, int n_in,
                              void* d_out, int out_size, void* d_ws, size_t ws_size,
                              hipStream_t stream) {
    const float* x      = (const float*)d_in[0];
    const float* W_in   = (const float*)d_in[1];
    const float* conv_w = (const float*)d_in[2];
    const float* conv_b = (const float*)d_in[3];
    const float* W_x    = (const float*)d_in[4];
    const float* W_dt   = (const float*)d_in[5];
    const float* b_dt   = (const float*)d_in[6];
    const float* A_log  = (const float*)d_in[7];
    const float* Dv     = (const float*)d_in[8];
    const float* W_out  = (const float*)d_in[9];
    float* out = (float*)d_out;

    // workspace layout (bytes); lifetime-based aliasing:
    //  R1 region: Win_bf(1-2) / part(4-5) at +16MB / summ(7-9) / Wout_bf(10-11)
    //  C  region: xc_bf(3-4) then g_bf(9-11)
    //  XBF region: x_bf(1-2)
    constexpr size_t OFF_XZ    = 0;           // 33554432  xz (L,4096) f32
    constexpr size_t OFF_XC    = 33554432;    // 16777216  xc f32
    constexpr size_t OFF_C     = 50331648;    //  8388608  xc_bf then g_bf
    constexpr size_t OFF_DELTA = 58720256;    // 16777216  delta f32
    constexpr size_t OFF_R1    = 75497472;    // 33554432  Win_bf | part(+16M) | summ | Wout_bf
    constexpr size_t OFF_XBF   = 109051904;   //  4194304  x_bf
    constexpr size_t OFF_DBC   = 113246208;   //   786432  dBC (L,96) f32
    constexpr size_t OFF_DLY   = 114032640;   //   262144  delta_r bf16
    constexpr size_t OFF_WX    = 114294784;   //   393216
    constexpr size_t OFF_WDT   = 114688000;   //   262144
    constexpr size_t WS_NEED   = 114950144;

    if (ws_size < WS_NEED) {   // loud, diagnosable failure
        k_fill<<<(out_size + 255) / 256, 256, 0, stream>>>(out, 1.0e9f, out_size);
        return;
    }

    char* ws = (char*)d_ws;
    float*  xz    = (float*)(ws + OFF_XZ);
    float*  xc    = (float*)(ws + OFF_XC);
    bf16_t* xc_bf = (bf16_t*)(ws + OFF_C);
    bf16_t* g_bf  = (bf16_t*)(ws + OFF_C);
    float*  delta = (float*)(ws + OFF_DELTA);
    bf16_t* Win_bf  = (bf16_t*)(ws + OFF_R1);
    float*  part    = (float*)(ws + OFF_R1 + 16777216);
    float4* summ    = (float4*)(ws + OFF_R1);
    bf16_t* Wout_bf = (bf16_t*)(ws + OFF_R1);
    bf16_t* x_bf  = (bf16_t*)(ws + OFF_XBF);
    float*  dBC   = (float*)(ws + OFF_DBC);
    bf16_t* dly   = (bf16_t*)(ws + OFF_DLY);
    bf16_t* Wx_bf  = (bf16_t*)(ws + OFF_WX);
    bf16_t* Wdt_bf = (bf16_t*)(ws + OFF_WDT);

    auto cvt = [&](const float* s, bf16_t* d, int n) {
        k_cvt4<<<(n / 4 + 255) / 256, 256, 0, stream>>>((const float4*)s, (bf16x4*)d, n / 4);
    };

    cvt(x, x_bf, L * DM);
    cvt(W_in, Win_bf, 2 * ED * DM);
    cvt(W_x, Wx_bf, 96 * ED);
    cvt(W_dt, Wdt_bf, ED * DTR);

    // GEMM1: xz = x @ W_in^T   (M=L, N=4096, K=DM)
    {
        dim3 g(4096 / 128, L / 128, 1);
        k_gemm_bt<0, false><<<g, 256, 0, stream>>>(x_bf, Win_bf, xz, L, 4096, DM, 4096, DM, nullptr);
    }
    k_conv_silu<<<L * ED / 256, 256, 0, stream>>>(xz, conv_w, conv_b, xc, xc_bf);
    // GEMM2 split-K: part[z] = xc @ W_x^T over k-range z  (M=L, N=96, K=ED)
    {
        dim3 g(1, L / 128, SPLITS);
        k_gemm_bt<0, true><<<g, 256, 0, stream>>>(xc_bf, Wx_bf, part, L, 96, ED, 96, ED / SPLITS, nullptr);
    }
    k_red2<<<L * 96 / 256, 256, 0, stream>>>(part, dBC, dly);
    // GEMM3: delta = softplus(dly @ W_dt^T + b_dt)  (M=L, N=ED, K=64)
    {
        dim3 g(ED / 128, L / 128, 1);
        k_gemm_bt<1, false><<<g, 256, 0, stream>>>(dly, Wdt_bf, delta, L, ED, DTR, ED, DTR, b_dt);
    }
    // chunked scan
    k_scan_p1<<<NCHUNK * 8, 256, 0, stream>>>(delta, xc, dBC, A_log, summ);
    k_combine<<<ED * NST / 256, 256, 0, stream>>>(summ);
    k_scan_p2<<<NCHUNK * 8, 256, 0, stream>>>(delta, xc, dBC, A_log, summ, Dv, xz, g_bf);
    // GEMM4: out = g @ W_out^T  (M=L, N=DM, K=ED)
    cvt(W_out, Wout_bf, DM * ED);
    {
        dim3 g(DM / 128, L / 128, 1);
        k_gemm_bt<0, false><<<g, 256, 0, stream>>>(g_bf, Wout_bf, out, L, DM, ED, DM, ED, nullptr);
    }
}

// Round 5
// 275.678 us; speedup vs baseline: 1.9157x; 1.0735x over previous
//
#include <hip/hip_runtime.h>
#include <hip/hip_bf16.h>
#include <math.h>

#define L 2048
#define DM 1024
#define ED 2048
#define NST 16
#define DTR 64
#define BETA 0.6f
#define NCHUNK 64
#define LCH 32            // L / NCHUNK
#define SPLITS 16         // GEMM2 split-K
#define SPLIT4 4          // GEMM4 split-K

typedef __bf16 bf16_t;
typedef __bf16 bf16x8 __attribute__((ext_vector_type(8)));
typedef __bf16 bf16x4 __attribute__((ext_vector_type(4)));
typedef float  floatx4 __attribute__((ext_vector_type(4)));

// ---------------- utility kernels ----------------

__global__ void k_fill(float* __restrict__ p, float v, int n) {
    int i = blockIdx.x * 256 + threadIdx.x;
    if (i < n) p[i] = v;
}

__global__ void k_cvt4(const float4* __restrict__ src, bf16x4* __restrict__ dst, int n4) {
    int i = blockIdx.x * 256 + threadIdx.x;
    if (i < n4) {
        float4 f = src[i];
        bf16x4 o;
        o[0] = (bf16_t)f.x; o[1] = (bf16_t)f.y; o[2] = (bf16_t)f.z; o[3] = (bf16_t)f.w;
        dst[i] = o;
    }
}

// ---------------- bf16 GEMM-BT:  C(M,N) = X(M,K) @ W(N,K)^T ----------------
// GUARD=false: N%128==0, uses global_load_lds width-16 staging (m97 pattern).
// GUARD=true : ragged N (zero-fill B rows >= N, guarded stores), VGPR staging.
// blockIdx.z = split-K index: k range [z*ksz, z*ksz+ksz), C += z*M*ldc.
// EPI 0: plain store. EPI 1: softplus(v + bias[col]).
template<int EPI, bool GUARD>
__global__ __launch_bounds__(256)
void k_gemm_bt(const bf16_t* __restrict__ X, const bf16_t* __restrict__ W,
               float* __restrict__ C, int M, int N, int K, int ldc, int ksz,
               const float* __restrict__ bias) {
    __shared__ bf16_t As[128 * 32];
    __shared__ bf16_t Bs[128 * 32];
    const int tid  = threadIdx.x;
    const int bx   = blockIdx.x, by = blockIdx.y;
    const int kbase = blockIdx.z * ksz;
    C += (size_t)blockIdx.z * M * ldc;
    const int wave = tid >> 6, lane = tid & 63;
    const int wm   = (wave >> 1) * 64;
    const int wn   = (wave & 1) * 64;
    const int quad = lane >> 4, l16 = lane & 15;

    floatx4 acc[4][4];
#pragma unroll
    for (int i = 0; i < 4; i++)
#pragma unroll
        for (int j = 0; j < 4; j++)
            acc[i][j] = (floatx4){0.f, 0.f, 0.f, 0.f};

    for (int kt = kbase; kt < kbase + ksz; kt += 32) {
        if (GUARD) {
#pragma unroll
            for (int p = 0; p < 2; p++) {
                int e = p * 2048 + tid * 8;
                int r = e >> 5, c = e & 31;
                int arow = by * 128 + r;
                *(float4*)(&As[r * 32 + c]) =
                    *(const float4*)(&X[(size_t)arow * K + kt + c]);
                int brow = bx * 128 + r;
                float4 bv = make_float4(0.f, 0.f, 0.f, 0.f);
                if (brow < N) bv = *(const float4*)(&W[(size_t)brow * K + kt + c]);
                *(float4*)(&Bs[r * 32 + c]) = bv;
            }
        } else {
            // async global->LDS, 16B/lane; LDS dest = wave-uniform base + lane*16
#pragma unroll
            for (int p = 0; p < 2; p++) {
                int e = p * 2048 + tid * 8;     // bf16 elem idx; byte off = p*4096 + tid*16
                int r = e >> 5, c = e & 31;
                __builtin_amdgcn_global_load_lds(
                    (const __attribute__((address_space(1))) void*)&X[(size_t)(by * 128 + r) * K + kt + c],
                    (__attribute__((address_space(3))) void*)&As[e], 16, 0, 0);
                __builtin_amdgcn_global_load_lds(
                    (const __attribute__((address_space(1))) void*)&W[(size_t)(bx * 128 + r) * K + kt + c],
                    (__attribute__((address_space(3))) void*)&Bs[e], 16, 0, 0);
            }
        }
        __syncthreads();

        bf16x8 af[4], bfr[4];
#pragma unroll
        for (int mt = 0; mt < 4; mt++)
            af[mt] = *(const bf16x8*)(&As[(wm + mt * 16 + l16) * 32 + quad * 8]);
#pragma unroll
        for (int nt = 0; nt < 4; nt++)
            bfr[nt] = *(const bf16x8*)(&Bs[(wn + nt * 16 + l16) * 32 + quad * 8]);
#pragma unroll
        for (int mt = 0; mt < 4; mt++)
#pragma unroll
            for (int nt = 0; nt < 4; nt++)
                acc[mt][nt] = __builtin_amdgcn_mfma_f32_16x16x32_bf16(
                    af[mt], bfr[nt], acc[mt][nt], 0, 0, 0);
        __syncthreads();
    }

    // epilogue: D layout col = lane&15, row = quad*4 + reg
#pragma unroll
    for (int mt = 0; mt < 4; mt++) {
#pragma unroll
        for (int nt = 0; nt < 4; nt++) {
            int col = bx * 128 + wn + nt * 16 + l16;
            if (!GUARD || col < N) {
#pragma unroll
                for (int r4 = 0; r4 < 4; r4++) {
                    int row = by * 128 + wm + mt * 16 + quad * 4 + r4;
                    float v = acc[mt][nt][r4];
                    if (EPI == 1) {
                        v += bias[col];
                        v = (v > 20.f) ? v : log1pf(__expf(v));
                    }
                    C[(size_t)row * ldc + col] = v;
                }
            }
        }
    }
}

// reduce GEMM4 split-K partials -> out, vectorized
__global__ void k_red4(const float4* __restrict__ part, float4* __restrict__ out) {
    int i = blockIdx.x * 256 + threadIdx.x;     // L*DM/4 threads
    const int stride = L * DM / 4;
    float4 a = part[i], b = part[i + stride];
    float4 c = part[i + 2 * stride], d = part[i + 3 * stride];
    out[i] = make_float4(a.x + b.x + c.x + d.x, a.y + b.y + c.y + d.y,
                         a.z + b.z + c.z + d.z, a.w + b.w + c.w + d.w);
}

// ---------------- depthwise causal conv (K=4) + silu ----------------
__global__ void k_conv_silu(const float* __restrict__ xz,
                            const float* __restrict__ conv_w,
                            const float* __restrict__ conv_b,
                            float* __restrict__ xc, bf16_t* __restrict__ xc_bf) {
    int idx = blockIdx.x * 256 + threadIdx.x;   // over L*ED
    int e = idx & (ED - 1);
    int t = idx >> 11;
    float w0 = conv_w[e * 4 + 0], w1 = conv_w[e * 4 + 1];
    float w2 = conv_w[e * 4 + 2], w3 = conv_w[e * 4 + 3];
    const float* col = xz + e;
    float acc = conv_b[e];
    if (t >= 3) acc += w0 * col[(size_t)(t - 3) * 4096];
    if (t >= 2) acc += w1 * col[(size_t)(t - 2) * 4096];
    if (t >= 1) acc += w2 * col[(size_t)(t - 1) * 4096];
    acc += w3 * col[(size_t)t * 4096];
    float s = acc / (1.f + __expf(-acc));       // silu
    xc[idx] = s;
    xc_bf[idx] = (bf16_t)s;
}

// reduce GEMM2 split-K partials -> dBC fp32; also emit dly bf16 (cols 0:64)
__global__ void k_red2(const float* __restrict__ part, float* __restrict__ dBC,
                       bf16_t* __restrict__ dly) {
    int idx = blockIdx.x * 256 + threadIdx.x;   // L*96
    int t = idx / 96, c = idx - t * 96;
    float s = 0.f;
#pragma unroll
    for (int sp = 0; sp < SPLITS; sp++) s += part[(size_t)sp * L * 96 + idx];
    dBC[idx] = s;
    if (c < 64) dly[t * 64 + c] = (bf16_t)s;
}

// ---------------- chunked scan: thread = (chunk, e), 16 n-states in regs ----
// recurrence per (e,n):  v_t = B*v_{t-1} + u_t ;  h_t = a_t*h_{t-1} + v_t
// pass1 computes transition summary (h,v,p,q) per chunk with zero init;
// combine turns summaries into incoming states (written in-place into .xy);
// pass2 re-runs the recurrence from the true incoming state and emits gated g.
// summ layout: [n][chunk][e] float4 -> coalesced per-instr access everywhere.

__global__ __launch_bounds__(256)
void k_scan_p1(const float* __restrict__ delta, const float* __restrict__ xc,
               const float* __restrict__ dBC, const float* __restrict__ A_log,
               float4* __restrict__ summ) {
    const int chunk = blockIdx.x >> 3;                 // 8 blocks per chunk
    const int e = (blockIdx.x & 7) * 256 + threadIdx.x;
    float A[NST];
#pragma unroll
    for (int n = 0; n < NST; n++) A[n] = -__expf(A_log[e * NST + n]);
    float h[NST], v[NST], p[NST], q[NST];
#pragma unroll
    for (int n = 0; n < NST; n++) { h[n] = 0.f; v[n] = 0.f; p[n] = 1.f; q[n] = 0.f; }
    float bp = 1.f;
    const int t0 = chunk * LCH;
    for (int i = 0; i < LCH; i++) {
        int t = t0 + i;                                // block-uniform
        float d   = delta[(size_t)t * ED + e];
        float xcv = xc[(size_t)t * ED + e];
        float du  = d * xcv;
        bp *= BETA;
        const float* Bp = &dBC[t * 96 + 64];           // wave-uniform -> scalar loads
#pragma unroll
        for (int n = 0; n < NST; n++) {
            float a = __expf(d * A[n]);
            v[n] = BETA * v[n] + du * Bp[n];
            h[n] = a * h[n] + v[n];
            p[n] *= a;
            q[n] = a * q[n] + bp;
        }
    }
#pragma unroll
    for (int n = 0; n < NST; n++)
        summ[((size_t)n * NCHUNK + chunk) * ED + e] = make_float4(h[n], v[n], p[n], q[n]);
}

// sequential over chunks; writes incoming state (h,v) in-place into summ .xy
__global__ void k_combine(float4* __restrict__ summ) {
    int tid = blockIdx.x * 256 + threadIdx.x;   // ED*NST threads; tid = n*ED + e
    int n = tid >> 11, e = tid & (ED - 1);
    float2* s2 = (float2*)summ;
    float h = 0.f, v = 0.f;
    const float bl = 7.9586611e-8f;             // 0.6^32
#pragma unroll 4
    for (int c = 0; c < NCHUNK; c++) {
        size_t idx = ((size_t)n * NCHUNK + c) * ED + e;
        float4 f = summ[idx];                   // (hL, vL, p, q)
        s2[idx * 2] = make_float2(h, v);        // incoming state for chunk c
        float hn = f.z * h + f.w * v + f.x;
        v = bl * v + f.y;
        h = hn;
    }
}

__global__ __launch_bounds__(256)
void k_scan_p2(const float* __restrict__ delta, const float* __restrict__ xc,
               const float* __restrict__ dBC, const float* __restrict__ A_log,
               const float4* __restrict__ summ, const float* __restrict__ Dvec,
               const float* __restrict__ xz, bf16_t* __restrict__ g) {
    const int chunk = blockIdx.x >> 3;
    const int e = (blockIdx.x & 7) * 256 + threadIdx.x;
    float A[NST];
#pragma unroll
    for (int n = 0; n < NST; n++) A[n] = -__expf(A_log[e * NST + n]);
    float h[NST], v[NST];
    const float2* s2 = (const float2*)summ;
#pragma unroll
    for (int n = 0; n < NST; n++) {
        float2 s = s2[(((size_t)n * NCHUNK + chunk) * ED + e) * 2];
        h[n] = s.x; v[n] = s.y;                 // true incoming state: no p/q needed
    }
    const float De = Dvec[e];
    const int t0 = chunk * LCH;
    for (int i = 0; i < LCH; i++) {
        int t = t0 + i;
        float d   = delta[(size_t)t * ED + e];
        float xcv = xc[(size_t)t * ED + e];
        float du  = d * xcv;
        const float* Bp = &dBC[t * 96 + 64];
        const float* Cp = &dBC[t * 96 + 80];
        float yacc = 0.f;
#pragma unroll
        for (int n = 0; n < NST; n++) {
            float a = __expf(d * A[n]);
            v[n] = BETA * v[n] + du * Bp[n];
            h[n] = a * h[n] + v[n];
            yacc += Cp[n] * h[n];
        }
        // fused gate: g = bf16((y + D*xc) * silu(z))
        float z = xz[(size_t)t * 4096 + ED + e];
        float sz = z / (1.f + __expf(-z));
        g[(size_t)t * ED + e] = (bf16_t)((yacc + De * xcv) * sz);
    }
}

// ---------------- launch ----------------

extern "C" void kernel_launch(void* const* d_in, const int* in_sizes, int n_in,
                              void* d_out, int out_size, void* d_ws, size_t ws_size,
                              hipStream_t stream) {
    const float* x      = (const float*)d_in[0];
    const float* W_in   = (const float*)d_in[1];
    const float* conv_w = (const float*)d_in[2];
    const float* conv_b = (const float*)d_in[3];
    const float* W_x    = (const float*)d_in[4];
    const float* W_dt   = (const float*)d_in[5];
    const float* b_dt   = (const float*)d_in[6];
    const float* A_log  = (const float*)d_in[7];
    const float* Dv     = (const float*)d_in[8];
    const float* W_out  = (const float*)d_in[9];
    float* out = (float*)d_out;

    // workspace layout (bytes); lifetime-based aliasing:
    //  XZ region: xz f32 (GEMM1..p2) then GEMM4 split-K partials (32MB)
    //  R1 region: Win_bf | part2 at +16MB | summ
    //  C  region: xc_bf then g_bf
    constexpr size_t OFF_XZ    = 0;           // 33554432
    constexpr size_t OFF_XC    = 33554432;    // 16777216  xc f32
    constexpr size_t OFF_C     = 50331648;    //  8388608  xc_bf then g_bf
    constexpr size_t OFF_DELTA = 58720256;    // 16777216  delta f32
    constexpr size_t OFF_R1    = 75497472;    // 33554432
    constexpr size_t OFF_XBF   = 109051904;   //  4194304  x_bf
    constexpr size_t OFF_DBC   = 113246208;   //   786432  dBC (L,96) f32
    constexpr size_t OFF_DLY   = 114032640;   //   262144  delta_r bf16
    constexpr size_t OFF_WX    = 114294784;   //   393216
    constexpr size_t OFF_WDT   = 114688000;   //   262144
    constexpr size_t OFF_WOUT  = 114950144;   //  4194304  Wout_bf (dedicated)
    constexpr size_t WS_NEED   = 119144448;

    if (ws_size < WS_NEED) {   // loud, diagnosable failure
        k_fill<<<(out_size + 255) / 256, 256, 0, stream>>>(out, 1.0e9f, out_size);
        return;
    }

    char* ws = (char*)d_ws;
    float*  xz    = (float*)(ws + OFF_XZ);
    float*  part4 = (float*)(ws + OFF_XZ);      // alias: xz dead after p2
    float*  xc    = (float*)(ws + OFF_XC);
    bf16_t* xc_bf = (bf16_t*)(ws + OFF_C);
    bf16_t* g_bf  = (bf16_t*)(ws + OFF_C);      // alias: xc_bf dead after GEMM2 (p2 uses xc f32)
    float*  delta = (float*)(ws + OFF_DELTA);
    bf16_t* Win_bf  = (bf16_t*)(ws + OFF_R1);
    float*  part2   = (float*)(ws + OFF_R1 + 16777216);
    float4* summ    = (float4*)(ws + OFF_R1);   // alias: Win/part2 dead after GEMM3
    bf16_t* x_bf  = (bf16_t*)(ws + OFF_XBF);
    float*  dBC   = (float*)(ws + OFF_DBC);
    bf16_t* dly   = (bf16_t*)(ws + OFF_DLY);
    bf16_t* Wx_bf  = (bf16_t*)(ws + OFF_WX);
    bf16_t* Wdt_bf = (bf16_t*)(ws + OFF_WDT);
    bf16_t* Wout_bf = (bf16_t*)(ws + OFF_WOUT);

    auto cvt = [&](const float* s, bf16_t* d, int n) {
        k_cvt4<<<(n / 4 + 255) / 256, 256, 0, stream>>>((const float4*)s, (bf16x4*)d, n / 4);
    };

    // proven round-3 conversion path (round-4's merged cvt implicated in crash)
    cvt(x, x_bf, L * DM);
    cvt(W_in, Win_bf, 2 * ED * DM);
    cvt(W_x, Wx_bf, 96 * ED);
    cvt(W_dt, Wdt_bf, ED * DTR);
    cvt(W_out, Wout_bf, DM * ED);

    // GEMM1: xz = x @ W_in^T   (M=L, N=4096, K=DM)
    {
        dim3 g(4096 / 128, L / 128, 1);
        k_gemm_bt<0, false><<<g, 256, 0, stream>>>(x_bf, Win_bf, xz, L, 4096, DM, 4096, DM, nullptr);
    }
    k_conv_silu<<<L * ED / 256, 256, 0, stream>>>(xz, conv_w, conv_b, xc, xc_bf);
    // GEMM2 split-K: part2[z] = xc @ W_x^T over k-range z  (M=L, N=96, K=ED)
    {
        dim3 g(1, L / 128, SPLITS);
        k_gemm_bt<0, true><<<g, 256, 0, stream>>>(xc_bf, Wx_bf, part2, L, 96, ED, 96, ED / SPLITS, nullptr);
    }
    k_red2<<<L * 96 / 256, 256, 0, stream>>>(part2, dBC, dly);
    // GEMM3: delta = softplus(dly @ W_dt^T + b_dt)  (M=L, N=ED, K=64)
    {
        dim3 g(ED / 128, L / 128, 1);
        k_gemm_bt<1, false><<<g, 256, 0, stream>>>(dly, Wdt_bf, delta, L, ED, DTR, ED, DTR, b_dt);
    }
    // chunked scan
    k_scan_p1<<<NCHUNK * 8, 256, 0, stream>>>(delta, xc, dBC, A_log, summ);
    k_combine<<<ED * NST / 256, 256, 0, stream>>>(summ);
    k_scan_p2<<<NCHUNK * 8, 256, 0, stream>>>(delta, xc, dBC, A_log, summ, Dv, xz, g_bf);
    // GEMM4 split-K: part4[z] = g @ W_out^T over k-range z  (M=L, N=DM, K=ED)
    {
        dim3 g(DM / 128, L / 128, SPLIT4);
        k_gemm_bt<0, false><<<g, 256, 0, stream>>>(g_bf, Wout_bf, part4, L, DM, ED, DM, ED / SPLIT4, nullptr);
    }
    k_red4<<<L * DM / 4 / 256, 256, 0, stream>>>((const float4*)part4, (float4*)out);
}